// Round 2
// baseline (2990.456 us; speedup 1.0000x reference)
//
#include <hip/hip_runtime.h>
#include <math.h>

#define B_DIM 4096
#define S_DIM 200
#define E_DIM 100
#define C_DIM 20
#define K_DIM 51
#define PADW  25
#define SP    (S_DIM + 2 * PADW)   // 250
#define EPS   1e-13f

// ---------------------------------------------------------------------------
// Prep: transpose conv weights to wt[(i*K+k)*C + o], labels to Lt[e*C + c],
// and compute label norms nl[c].  All live in d_ws.
// ---------------------------------------------------------------------------
__global__ void prep_kernel(const float* __restrict__ conv_w,
                            const float* __restrict__ labels,
                            float* __restrict__ wt,
                            float* __restrict__ Lt,
                            float* __restrict__ nl) {
    int idx = blockIdx.x * 256 + threadIdx.x;
    const int NWT = C_DIM * C_DIM * K_DIM;   // 20400
    const int NLT = C_DIM * E_DIM;           // 2000
    if (idx < NWT) {
        int ik = idx / C_DIM;
        int o  = idx % C_DIM;
        int i  = ik / K_DIM;
        int k  = ik % K_DIM;
        wt[idx] = conv_w[(o * C_DIM + i) * K_DIM + k];
    } else if (idx < NWT + NLT) {
        int j = idx - NWT;
        int e = j / C_DIM;
        int c = j % C_DIM;
        Lt[j] = labels[c * E_DIM + e];
    } else if (idx < NWT + NLT + C_DIM) {
        int c = idx - (NWT + NLT);
        float s = 0.f;
        for (int e = 0; e < E_DIM; ++e) {
            float v = labels[c * E_DIM + e];
            s += v * v;
        }
        nl[c] = sqrtf(s);
    }
}

// ---------------------------------------------------------------------------
// Fused per-batch-row kernel: one block (256 threads) per b.
// Thread s keeps its token's embedding row (100 f32) in registers the whole
// time; g tile lives in LDS; conv accumulators live in registers.
// ---------------------------------------------------------------------------
__launch_bounds__(256)
__global__ void fused_kernel(const int* __restrict__ x,
                             const int* __restrict__ mask,     // bool -> int32
                             const float* __restrict__ emb,
                             const float* __restrict__ conv_b,
                             const float* __restrict__ w1,
                             const float* __restrict__ b1,
                             const float* __restrict__ w2,
                             const float* __restrict__ b2,
                             const float* __restrict__ wt,
                             const float* __restrict__ Lt,
                             const float* __restrict__ nl,
                             float* __restrict__ out) {
    __shared__ float g_pad[C_DIM][SP];      // 20 KB, zero-padded conv input
    __shared__ float red[256];              // softmax reductions
    __shared__ float partial[4][E_DIM];     // per-wave pooling partials
    __shared__ float zsh[E_DIM];
    __shared__ float hsh[E_DIM / 2];

    const int tid  = threadIdx.x;
    const int b    = blockIdx.x;
    const int lane = tid & 63;
    const int wv   = tid >> 6;

    // zero the g tile (covers the PADW zero borders)
    for (int i = tid; i < C_DIM * SP; i += 256) ((float*)g_pad)[i] = 0.f;

    const int  s   = tid;
    const bool act = (s < S_DIM);
    const int  tok = act ? x[b * S_DIM + s] : 0;

    // ---- gather embedding row into registers (held through all phases) ----
    float4 rr[25];
    const float4* er = (const float4*)(emb + (size_t)tok * E_DIM);
#pragma unroll
    for (int j = 0; j < 25; ++j) rr[j] = er[j];

    // ---- row norm ----
    float n2 = 0.f;
#pragma unroll
    for (int j = 0; j < 25; ++j)
        n2 += rr[j].x * rr[j].x + rr[j].y * rr[j].y + rr[j].z * rr[j].z + rr[j].w * rr[j].w;
    const float xn = sqrtf(n2);

    // ---- dots with all 20 labels via transposed Lt (uniform loads) ----
    float dacc[C_DIM];
#pragma unroll
    for (int c = 0; c < C_DIM; ++c) dacc[c] = 0.f;
    const float4* Lt4 = (const float4*)Lt;
#pragma unroll
    for (int j = 0; j < 25; ++j) {
        const float rv[4] = {rr[j].x, rr[j].y, rr[j].z, rr[j].w};
#pragma unroll
        for (int u = 0; u < 4; ++u) {
            const int e = j * 4 + u;
#pragma unroll
            for (int q = 0; q < 5; ++q) {
                const float4 a = Lt4[e * 5 + q];
                dacc[q * 4 + 0] += rv[u] * a.x;
                dacc[q * 4 + 1] += rv[u] * a.y;
                dacc[q * 4 + 2] += rv[u] * a.z;
                dacc[q * 4 + 3] += rv[u] * a.w;
            }
        }
    }

    if (act) {
#pragma unroll
        for (int c = 0; c < C_DIM; ++c) {
            float gh = nl[c] * xn;
            gh = (gh == 0.f) ? EPS : gh;
            g_pad[c][PADW + s] = dacc[c] / gh;   // cosine similarity
        }
    }
    __syncthreads();

    // ---- conv: u[o,s] = sum_{i,k} g_pad[i][s+k] * w[o,i,k] ----
    float acc[C_DIM];
#pragma unroll
    for (int c = 0; c < C_DIM; ++c) acc[c] = 0.f;
    const int sc = act ? s : 0;
    const float4* wt4 = (const float4*)wt;
    for (int i = 0; i < C_DIM; ++i) {
        const float* grow = &g_pad[i][sc];
#pragma unroll
        for (int k = 0; k < K_DIM; ++k) {
            const float gv = grow[k];                 // stride-1 lanes: conflict-free
            const int wb = (i * K_DIM + k) * 5;
            const float4 a0 = wt4[wb + 0];
            const float4 a1 = wt4[wb + 1];
            const float4 a2 = wt4[wb + 2];
            const float4 a3 = wt4[wb + 3];
            const float4 a4 = wt4[wb + 4];
            acc[0]  += gv * a0.x;  acc[1]  += gv * a0.y;  acc[2]  += gv * a0.z;  acc[3]  += gv * a0.w;
            acc[4]  += gv * a1.x;  acc[5]  += gv * a1.y;  acc[6]  += gv * a1.z;  acc[7]  += gv * a1.w;
            acc[8]  += gv * a2.x;  acc[9]  += gv * a2.y;  acc[10] += gv * a2.z;  acc[11] += gv * a2.w;
            acc[12] += gv * a3.x;  acc[13] += gv * a3.y;  acc[14] += gv * a3.z;  acc[15] += gv * a3.w;
            acc[16] += gv * a4.x;  acc[17] += gv * a4.y;  acc[18] += gv * a4.z;  acc[19] += gv * a4.w;
        }
    }

    // ---- relu + bias + max over channels ----
    float m_s = 0.f;   // relu floor: max(relu(v)) == max(0, max(v))
#pragma unroll
    for (int c = 0; c < C_DIM; ++c) m_s = fmaxf(m_s, acc[c] + conv_b[c]);

    float mval;
    if (act) mval = (mask[b * S_DIM + s] != 0) ? m_s : -1e13f;  // reference -INF = -1e13
    else     mval = -1e30f;                                     // padding lanes: exp -> 0

    // ---- block softmax over s ----
    red[tid] = mval;
    __syncthreads();
    for (int off = 128; off > 0; off >>= 1) {
        if (tid < off) red[tid] = fmaxf(red[tid], red[tid + off]);
        __syncthreads();
    }
    const float gmax = red[0];
    __syncthreads();
    const float p = expf(mval - gmax);
    red[tid] = p;
    __syncthreads();
    for (int off = 128; off > 0; off >>= 1) {
        if (tid < off) red[tid] += red[tid + off];
        __syncthreads();
    }
    const float gsum = red[0];
    const float bs = p / gsum;   // softmax weight for this token (0 for pads)

    // ---- weighted pooling: z[e] = sum_s bs * xx[s][e] (wave butterflies) ----
#pragma unroll
    for (int j = 0; j < 25; ++j) {
        float c0 = rr[j].x * bs, c1 = rr[j].y * bs, c2 = rr[j].z * bs, c3 = rr[j].w * bs;
#pragma unroll
        for (int off = 32; off > 0; off >>= 1) {
            c0 += __shfl_xor(c0, off);
            c1 += __shfl_xor(c1, off);
            c2 += __shfl_xor(c2, off);
            c3 += __shfl_xor(c3, off);
        }
        if (lane == 0) {
            partial[wv][j * 4 + 0] = c0;
            partial[wv][j * 4 + 1] = c1;
            partial[wv][j * 4 + 2] = c2;
            partial[wv][j * 4 + 3] = c3;
        }
    }
    __syncthreads();
    if (tid < E_DIM)
        zsh[tid] = partial[0][tid] + partial[1][tid] + partial[2][tid] + partial[3][tid];
    __syncthreads();

    // ---- MLP: h = relu(z @ w1 + b1); out = h @ w2 + b2 ----
    if (tid < E_DIM / 2) {
        float h = b1[tid];
        for (int e = 0; e < E_DIM; ++e) h += zsh[e] * w1[e * (E_DIM / 2) + tid];
        hsh[tid] = fmaxf(h, 0.f);
    }
    __syncthreads();
    if (tid < C_DIM) {
        float o = b2[tid];
#pragma unroll
        for (int j = 0; j < E_DIM / 2; ++j) o += hsh[j] * w2[j * C_DIM + tid];
        out[b * C_DIM + tid] = o;
    }
}

// ---------------------------------------------------------------------------
extern "C" void kernel_launch(void* const* d_in, const int* in_sizes, int n_in,
                              void* d_out, int out_size, void* d_ws, size_t ws_size,
                              hipStream_t stream) {
    const int*   x      = (const int*)d_in[0];
    // d_in[1] = x_len (unused by reference)
    const int*   mask   = (const int*)d_in[2];    // bool delivered as int32
    const float* emb    = (const float*)d_in[3];
    const float* labels = (const float*)d_in[4];
    const float* conv_w = (const float*)d_in[5];
    const float* conv_b = (const float*)d_in[6];
    const float* w1     = (const float*)d_in[7];
    const float* b1     = (const float*)d_in[8];
    const float* w2     = (const float*)d_in[9];
    const float* b2     = (const float*)d_in[10];
    float*       out    = (float*)d_out;

    float* wt = (float*)d_ws;        // 20400 floats (16B-aligned)
    float* Lt = wt + 20400;          // 2000 floats  (offset 81600B, 16B-aligned)
    float* nl = Lt + 2000;           // 20 floats

    prep_kernel<<<88, 256, 0, stream>>>(conv_w, labels, wt, Lt, nl);
    fused_kernel<<<B_DIM, 256, 0, stream>>>(x, mask, emb, conv_b,
                                            w1, b1, w2, b2, wt, Lt, nl, out);
}

// Round 3
// 2128.269 us; speedup vs baseline: 1.4051x; 1.4051x over previous
//
#include <hip/hip_runtime.h>
#include <math.h>

#define B_DIM 4096
#define S_DIM 200
#define E_DIM 100
#define C_DIM 20
#define K_DIM 51
#define PADW  25
#define SP    (S_DIM + 2 * PADW)   // 250
#define WPT   4                    // s-positions per thread

// ---------------------------------------------------------------------------
// Prep: wt[(i*K+k)*C + o] (conv weights transposed), Lt[e*C + c] (labels
// transposed), rnl[c] = 1/||label_c||.  All in d_ws.
// ---------------------------------------------------------------------------
__global__ void prep_kernel(const float* __restrict__ conv_w,
                            const float* __restrict__ labels,
                            float* __restrict__ wt,
                            float* __restrict__ Lt,
                            float* __restrict__ rnl) {
    int idx = blockIdx.x * 256 + threadIdx.x;
    const int NWT = C_DIM * C_DIM * K_DIM;   // 20400
    const int NLT = C_DIM * E_DIM;           // 2000
    if (idx < NWT) {
        int ik = idx / C_DIM;
        int o  = idx % C_DIM;
        int i  = ik / K_DIM;
        int k  = ik % K_DIM;
        wt[idx] = conv_w[(o * C_DIM + i) * K_DIM + k];
    } else if (idx < NWT + NLT) {
        int j = idx - NWT;
        int e = j / C_DIM;
        int c = j % C_DIM;
        Lt[j] = labels[c * E_DIM + e];
    } else if (idx < NWT + NLT + C_DIM) {
        int c = idx - (NWT + NLT);
        float s = 0.f;
        for (int e = 0; e < E_DIM; ++e) {
            float v = labels[c * E_DIM + e];
            s += v * v;
        }
        float n = sqrtf(s);
        rnl[c] = (n > 0.f) ? 1.f / n : 0.f;
    }
}

// ---------------------------------------------------------------------------
// One wave (64 threads) per batch row.  Thread t owns s = 4t..4t+3
// (t in [0,50); lanes 50..63 duplicate t=49's work, harmlessly).
// Conv: acc[4][20] register tile, rolling LDS window -> 80 FMAs per
// (1 ds_read + 5 uniform weight loads).
// ---------------------------------------------------------------------------
__launch_bounds__(64)
__global__ void fused_kernel(const int* __restrict__ x,
                             const int* __restrict__ mask,     // bool -> int32
                             const float* __restrict__ emb,
                             const float* __restrict__ conv_b,
                             const float* __restrict__ w1,
                             const float* __restrict__ b1,
                             const float* __restrict__ w2,
                             const float* __restrict__ b2,
                             const float* __restrict__ wt,
                             const float* __restrict__ Lt,
                             const float* __restrict__ rnl,
                             float* __restrict__ out) {
    __shared__ float g_pad[C_DIM][SP];   // 20 KB zero-padded conv input
    __shared__ float bw[S_DIM];          // softmax weights by s
    __shared__ int   toks[S_DIM];        // token ids by s
    __shared__ float zsh[E_DIM];
    __shared__ float hsh[E_DIM / 2];

    const int tid = threadIdx.x;
    const int b   = blockIdx.x;

    // ---- zero the g tile (covers PADW borders) ----
    float4* gz = (float4*)&g_pad[0][0];                // 1250 float4
    for (int j = tid; j < C_DIM * SP / 4; j += 64) gz[j] = float4{0.f, 0.f, 0.f, 0.f};

    const bool own = (tid < S_DIM / WPT);              // 50 owner lanes
    const int  sc  = own ? tid * WPT : S_DIM - WPT;    // dup lanes redo s=196..199

    int tok[WPT], msk[WPT];
#pragma unroll
    for (int d = 0; d < WPT; ++d) {
        tok[d] = x[b * S_DIM + sc + d];
        msk[d] = mask[b * S_DIM + sc + d];
    }
    if (own) {
#pragma unroll
        for (int d = 0; d < WPT; ++d) toks[sc + d] = tok[d];
    }
    __syncthreads();

    // ---- phase 1: cosine similarities -> g_pad ----
    const float4* Lt4 = (const float4*)Lt;
#pragma unroll
    for (int d = 0; d < WPT; ++d) {
        const float4* er = (const float4*)(emb + (size_t)tok[d] * E_DIM);
        float dacc[C_DIM];
#pragma unroll
        for (int c = 0; c < C_DIM; ++c) dacc[c] = 0.f;
        float n2 = 0.f;
#pragma unroll
        for (int j = 0; j < 25; ++j) {
            const float4 r = er[j];
            n2 += r.x * r.x + r.y * r.y + r.z * r.z + r.w * r.w;
            const float rv[4] = {r.x, r.y, r.z, r.w};
#pragma unroll
            for (int u = 0; u < 4; ++u) {
#pragma unroll
                for (int q = 0; q < 5; ++q) {
                    const float4 a = Lt4[(j * 4 + u) * 5 + q];
                    dacc[q * 4 + 0] += rv[u] * a.x;
                    dacc[q * 4 + 1] += rv[u] * a.y;
                    dacc[q * 4 + 2] += rv[u] * a.z;
                    dacc[q * 4 + 3] += rv[u] * a.w;
                }
            }
        }
        const float xn  = sqrtf(n2);
        const float rxn = (xn > 0.f) ? 1.f / xn : 0.f;
#pragma unroll
        for (int c = 0; c < C_DIM; ++c)
            g_pad[c][PADW + sc + d] = dacc[c] * rnl[c] * rxn;
    }
    __syncthreads();

    // ---- conv: u[o, sc+d] = sum_{i,k} g_pad_raw[i][sc+d+k] * w[o,i,k] ----
    float acc[WPT][C_DIM];
#pragma unroll
    for (int d = 0; d < WPT; ++d)
#pragma unroll
        for (int o = 0; o < C_DIM; ++o) acc[d][o] = 0.f;

    const float4* wt4 = (const float4*)wt;
    for (int i = 0; i < C_DIM; ++i) {
        const float* grow = &g_pad[i][sc];
        float h0 = grow[0], h1 = grow[1], h2 = grow[2];
#pragma unroll 4
        for (int k = 0; k < K_DIM; ++k) {
            const float h3 = grow[k + 3];
            const float4* wp = wt4 + (size_t)(i * K_DIM + k) * 5;
#pragma unroll
            for (int q = 0; q < 5; ++q) {
                const float4 w = wp[q];
                acc[0][q * 4 + 0] += h0 * w.x;  acc[0][q * 4 + 1] += h0 * w.y;
                acc[0][q * 4 + 2] += h0 * w.z;  acc[0][q * 4 + 3] += h0 * w.w;
                acc[1][q * 4 + 0] += h1 * w.x;  acc[1][q * 4 + 1] += h1 * w.y;
                acc[1][q * 4 + 2] += h1 * w.z;  acc[1][q * 4 + 3] += h1 * w.w;
                acc[2][q * 4 + 0] += h2 * w.x;  acc[2][q * 4 + 1] += h2 * w.y;
                acc[2][q * 4 + 2] += h2 * w.z;  acc[2][q * 4 + 3] += h2 * w.w;
                acc[3][q * 4 + 0] += h3 * w.x;  acc[3][q * 4 + 1] += h3 * w.y;
                acc[3][q * 4 + 2] += h3 * w.z;  acc[3][q * 4 + 3] += h3 * w.w;
            }
            h0 = h1; h1 = h2; h2 = h3;
        }
    }

    // ---- relu + bias + channel max, then wave softmax over s ----
    float mv[WPT];
#pragma unroll
    for (int d = 0; d < WPT; ++d) {
        float m = 0.f;   // relu floor
#pragma unroll
        for (int o = 0; o < C_DIM; ++o) m = fmaxf(m, acc[d][o] + conv_b[o]);
        mv[d] = (msk[d] != 0) ? m : -1e13f;
    }
    float lm = fmaxf(fmaxf(mv[0], mv[1]), fmaxf(mv[2], mv[3]));
#pragma unroll
    for (int off = 32; off > 0; off >>= 1) lm = fmaxf(lm, __shfl_xor(lm, off));

    float p[WPT], ps = 0.f;
#pragma unroll
    for (int d = 0; d < WPT; ++d) { p[d] = expf(mv[d] - lm); ps += p[d]; }
    if (!own) ps = 0.f;   // duplicate lanes must not contribute to the sum
#pragma unroll
    for (int off = 32; off > 0; off >>= 1) ps += __shfl_xor(ps, off);
    const float rs = 1.f / ps;
    if (own) {
#pragma unroll
        for (int d = 0; d < WPT; ++d) bw[sc + d] = p[d] * rs;
    }
    __syncthreads();

    // ---- pooling: z[e] = sum_s bw[s] * emb[toks[s]][e]  (coalesced sweep) ----
    float za = 0.f, zb = 0.f;
    for (int s = 0; s < S_DIM; ++s) {
        const float  w   = bw[s];                              // uniform LDS
        const float* row = emb + (size_t)toks[s] * E_DIM;      // uniform LDS
        za += w * row[tid];
        if (tid < E_DIM - 64) zb += w * row[64 + tid];
    }
    zsh[tid] = za;
    if (tid < E_DIM - 64) zsh[64 + tid] = zb;
    __syncthreads();

    // ---- MLP ----
    if (tid < E_DIM / 2) {
        float h = b1[tid];
        for (int e = 0; e < E_DIM; ++e) h += zsh[e] * w1[e * (E_DIM / 2) + tid];
        hsh[tid] = fmaxf(h, 0.f);
    }
    __syncthreads();
    if (tid < C_DIM) {
        float o = b2[tid];
#pragma unroll
        for (int j = 0; j < E_DIM / 2; ++j) o += hsh[j] * w2[j * C_DIM + tid];
        out[b * C_DIM + tid] = o;
    }
}

// ---------------------------------------------------------------------------
extern "C" void kernel_launch(void* const* d_in, const int* in_sizes, int n_in,
                              void* d_out, int out_size, void* d_ws, size_t ws_size,
                              hipStream_t stream) {
    const int*   x      = (const int*)d_in[0];
    // d_in[1] = x_len (unused by reference)
    const int*   mask   = (const int*)d_in[2];    // bool delivered as int32
    const float* emb    = (const float*)d_in[3];
    const float* labels = (const float*)d_in[4];
    const float* conv_w = (const float*)d_in[5];
    const float* conv_b = (const float*)d_in[6];
    const float* w1     = (const float*)d_in[7];
    const float* b1     = (const float*)d_in[8];
    const float* w2     = (const float*)d_in[9];
    const float* b2     = (const float*)d_in[10];
    float*       out    = (float*)d_out;

    float* wt  = (float*)d_ws;       // 20400 floats
    float* Lt  = wt + 20400;         // 2000 floats
    float* rnl = Lt + 2000;          // 20 floats

    prep_kernel<<<88, 256, 0, stream>>>(conv_w, labels, wt, Lt, rnl);
    fused_kernel<<<B_DIM, 64, 0, stream>>>(x, mask, emb, conv_b,
                                           w1, b1, w2, b2, wt, Lt, rnl, out);
}

// Round 4
// 960.948 us; speedup vs baseline: 3.1120x; 2.2148x over previous
//
#include <hip/hip_runtime.h>
#include <math.h>

#define B_DIM 4096
#define S_DIM 200
#define E_DIM 100
#define C_DIM 20
#define K_DIM 51
#define KP    52                    // k zero-padded to 52 (13 groups of 4)
#define PADW  25
#define SP    252                   // 250 rounded up so row stride = 1008 B (16-aligned)
#define WPT   4
#define NCH   10                    // weight chunks, 2 input channels each
#define CH_F  2304                  // floats per chunk (2*52*20=2080, padded to 576 float4)
#define CH_V4 576

// ---------------------------------------------------------------------------
// Prep: padded/transposed weight image wt_p[ch][(ii*52+k)*20+o] (k=51 -> 0),
// Lt[e*20+c] transposed labels, rnl[c] = 1/||label_c||.
// ---------------------------------------------------------------------------
__global__ void prep_kernel(const float* __restrict__ conv_w,
                            const float* __restrict__ labels,
                            float* __restrict__ wt_p,
                            float* __restrict__ Lt,
                            float* __restrict__ rnl) {
    int idx = blockIdx.x * 256 + threadIdx.x;
    const int NW = NCH * CH_F;                 // 23040
    if (idx < NW) {
        int ch = idx / CH_F, r = idx % CH_F;
        float v = 0.f;
        if (r < 2 * KP * C_DIM) {              // 2080 valid slots
            int ii = r / (KP * C_DIM);
            int rr = r % (KP * C_DIM);
            int k  = rr / C_DIM, o = rr % C_DIM;
            int i  = ch * 2 + ii;
            if (k < K_DIM) v = conv_w[(o * C_DIM + i) * K_DIM + k];
        }
        wt_p[idx] = v;
    } else if (idx < NW + C_DIM * E_DIM) {
        int j = idx - NW;
        int e = j / C_DIM, c = j % C_DIM;
        Lt[j] = labels[c * E_DIM + e];
    } else if (idx < NW + C_DIM * E_DIM + C_DIM) {
        int c = idx - NW - C_DIM * E_DIM;
        float s = 0.f;
        for (int e = 0; e < E_DIM; ++e) { float v = labels[c * E_DIM + e]; s += v * v; }
        float n = sqrtf(s);
        rnl[c] = (n > 0.f) ? 1.f / n : 0.f;
    }
}

// ---------------------------------------------------------------------------
// One wave per batch row.  Weights stream global -> regs -> LDS in chunks;
// conv reads them as broadcast ds_read_b128 (ordered returns, partial waits).
// ---------------------------------------------------------------------------
__launch_bounds__(64)
__global__ void fused_kernel(const int* __restrict__ x,
                             const int* __restrict__ mask,     // bool -> int32
                             const float* __restrict__ emb,
                             const float* __restrict__ conv_b,
                             const float* __restrict__ w1,
                             const float* __restrict__ b1,
                             const float* __restrict__ w2,
                             const float* __restrict__ b2,
                             const float* __restrict__ wt_p,
                             const float* __restrict__ Lt,
                             const float* __restrict__ rnl,
                             float* __restrict__ out) {
    __shared__ float g_pad[C_DIM][SP];   // 20160 B zero-padded conv input
    __shared__ float wlds[CH_F];         // 9216 B: Lt during phase 1, then weight chunks
    __shared__ float bw[S_DIM];
    __shared__ int   toks[S_DIM];
    __shared__ float zsh[E_DIM];
    __shared__ float hsh[E_DIM / 2];

    const int tid = threadIdx.x;
    const int b   = blockIdx.x;

    // ---- zero g tile ----
    float4* gz = (float4*)&g_pad[0][0];                 // 1260 float4
    for (int r = 0; r < 20; ++r) {
        int j = r * 64 + tid;
        if (j < C_DIM * SP / 4) gz[j] = float4{0.f, 0.f, 0.f, 0.f};
    }

    // ---- stage Lt (500 float4) into wlds ----
    {
        const float4* Lg = (const float4*)Lt;
        float4* w4 = (float4*)wlds;
#pragma unroll
        for (int r = 0; r < 8; ++r) {
            int j = r * 64 + tid;
            if (j < 500) w4[j] = Lg[j];
        }
    }

    const bool own = (tid < S_DIM / WPT);               // 50 owner lanes
    const int  sc  = own ? tid * WPT : S_DIM - WPT;

    int tok[WPT], msk[WPT];
#pragma unroll
    for (int d = 0; d < WPT; ++d) {
        tok[d] = x[b * S_DIM + sc + d];
        msk[d] = mask[b * S_DIM + sc + d];
    }
    if (own) {
#pragma unroll
        for (int d = 0; d < WPT; ++d) toks[sc + d] = tok[d];
    }
    __syncthreads();

    // ---- phase 1: cosine sims; each Lt vector feeds all 4 s-positions ----
    {
        float dacc[WPT][C_DIM];
        float n2[WPT] = {0.f, 0.f, 0.f, 0.f};
#pragma unroll
        for (int d = 0; d < WPT; ++d)
#pragma unroll
            for (int c = 0; c < C_DIM; ++c) dacc[d][c] = 0.f;

        const float4* wl4 = (const float4*)wlds;
        for (int j = 0; j < 25; ++j) {
            float4 r4[WPT];
#pragma unroll
            for (int d = 0; d < WPT; ++d)
                r4[d] = *(const float4*)(emb + (size_t)tok[d] * E_DIM + j * 4);
#pragma unroll
            for (int d = 0; d < WPT; ++d)
                n2[d] += r4[d].x * r4[d].x + r4[d].y * r4[d].y +
                         r4[d].z * r4[d].z + r4[d].w * r4[d].w;
#pragma unroll
            for (int u = 0; u < 4; ++u) {
                float rv[WPT];
#pragma unroll
                for (int d = 0; d < WPT; ++d) rv[d] = ((const float*)&r4[d])[u];
#pragma unroll
                for (int q = 0; q < 5; ++q) {
                    const float4 a = wl4[(j * 4 + u) * 5 + q];
#pragma unroll
                    for (int d = 0; d < WPT; ++d) {
                        dacc[d][q * 4 + 0] += rv[d] * a.x;
                        dacc[d][q * 4 + 1] += rv[d] * a.y;
                        dacc[d][q * 4 + 2] += rv[d] * a.z;
                        dacc[d][q * 4 + 3] += rv[d] * a.w;
                    }
                }
            }
        }
#pragma unroll
        for (int d = 0; d < WPT; ++d) {
            const float xn  = sqrtf(n2[d]);
            const float rxn = (xn > 0.f) ? 1.f / xn : 0.f;
#pragma unroll
            for (int c = 0; c < C_DIM; ++c)
                g_pad[c][PADW + sc + d] = dacc[d][c] * rnl[c] * rxn;
        }
    }
    __syncthreads();

    // ---- conv with LDS-staged weight chunks (prefetch 1 ahead) ----
    float acc[WPT][C_DIM];
#pragma unroll
    for (int d = 0; d < WPT; ++d)
#pragma unroll
        for (int o = 0; o < C_DIM; ++o) acc[d][o] = 0.f;

    const float4* wg = (const float4*)wt_p;
    float4 st[9];
#pragma unroll
    for (int r = 0; r < 9; ++r) st[r] = wg[r * 64 + tid];   // chunk 0

    for (int ch = 0; ch < NCH; ++ch) {
        __syncthreads();                        // prev readers of wlds done
        {
            float4* w4 = (float4*)wlds;
#pragma unroll
            for (int r = 0; r < 9; ++r) w4[r * 64 + tid] = st[r];
        }
        __syncthreads();
        if (ch + 1 < NCH) {
#pragma unroll
            for (int r = 0; r < 9; ++r) st[r] = wg[(ch + 1) * CH_V4 + r * 64 + tid];
        }
#pragma unroll
        for (int ii = 0; ii < 2; ++ii) {
            const float* grow = &g_pad[ch * 2 + ii][sc];
            float4 win = *(const float4*)&grow[0];
            float w0 = win.x, w1 = win.y, w2 = win.z, w3 = win.w;
#pragma unroll 1
            for (int G = 0; G < 13; ++G) {
                const int kg = G * 4;
                const float4 nx = *(const float4*)&grow[kg + 4];
                const float* wrow = &wlds[(ii * KP + kg) * C_DIM];
                const float h[7] = {w0, w1, w2, w3, nx.x, nx.y, nx.z};
#pragma unroll
                for (int dk = 0; dk < 4; ++dk) {
                    const float4* wp = (const float4*)&wrow[dk * C_DIM];
#pragma unroll
                    for (int q = 0; q < 5; ++q) {
                        const float4 w = wp[q];
                        acc[0][q * 4 + 0] += h[dk + 0] * w.x;
                        acc[0][q * 4 + 1] += h[dk + 0] * w.y;
                        acc[0][q * 4 + 2] += h[dk + 0] * w.z;
                        acc[0][q * 4 + 3] += h[dk + 0] * w.w;
                        acc[1][q * 4 + 0] += h[dk + 1] * w.x;
                        acc[1][q * 4 + 1] += h[dk + 1] * w.y;
                        acc[1][q * 4 + 2] += h[dk + 1] * w.z;
                        acc[1][q * 4 + 3] += h[dk + 1] * w.w;
                        acc[2][q * 4 + 0] += h[dk + 2] * w.x;
                        acc[2][q * 4 + 1] += h[dk + 2] * w.y;
                        acc[2][q * 4 + 2] += h[dk + 2] * w.z;
                        acc[2][q * 4 + 3] += h[dk + 2] * w.w;
                        acc[3][q * 4 + 0] += h[dk + 3] * w.x;
                        acc[3][q * 4 + 1] += h[dk + 3] * w.y;
                        acc[3][q * 4 + 2] += h[dk + 3] * w.z;
                        acc[3][q * 4 + 3] += h[dk + 3] * w.w;
                    }
                }
                w0 = nx.x; w1 = nx.y; w2 = nx.z; w3 = nx.w;
            }
        }
    }

    // ---- relu + bias + channel max, wave softmax over s ----
    float mv[WPT];
#pragma unroll
    for (int d = 0; d < WPT; ++d) {
        float m = 0.f;
#pragma unroll
        for (int o = 0; o < C_DIM; ++o) m = fmaxf(m, acc[d][o] + conv_b[o]);
        mv[d] = (msk[d] != 0) ? m : -1e13f;
    }
    float lm = fmaxf(fmaxf(mv[0], mv[1]), fmaxf(mv[2], mv[3]));
#pragma unroll
    for (int off = 32; off > 0; off >>= 1) lm = fmaxf(lm, __shfl_xor(lm, off));

    float p[WPT], ps = 0.f;
#pragma unroll
    for (int d = 0; d < WPT; ++d) { p[d] = expf(mv[d] - lm); ps += p[d]; }
    if (!own) ps = 0.f;
#pragma unroll
    for (int off = 32; off > 0; off >>= 1) ps += __shfl_xor(ps, off);
    const float rs = 1.f / ps;
    if (own) {
#pragma unroll
        for (int d = 0; d < WPT; ++d) bw[sc + d] = p[d] * rs;
    }
    __syncthreads();

    // ---- pooling: z[e] = sum_s bw[s] * emb[toks[s]][e] ----
    float za = 0.f, zb = 0.f;
    for (int s = 0; s < S_DIM; ++s) {
        const float  w   = bw[s];
        const float* row = emb + (size_t)toks[s] * E_DIM;
        za += w * row[tid];
        if (tid < E_DIM - 64) zb += w * row[64 + tid];
    }
    zsh[tid] = za;
    if (tid < E_DIM - 64) zsh[64 + tid] = zb;
    __syncthreads();

    // ---- MLP ----
    if (tid < E_DIM / 2) {
        float h = b1[tid];
        for (int e = 0; e < E_DIM; ++e) h += zsh[e] * w1[e * (E_DIM / 2) + tid];
        hsh[tid] = fmaxf(h, 0.f);
    }
    __syncthreads();
    if (tid < C_DIM) {
        float o = b2[tid];
#pragma unroll
        for (int j = 0; j < E_DIM / 2; ++j) o += hsh[j] * w2[j * C_DIM + tid];
        out[b * C_DIM + tid] = o;
    }
}

// ---------------------------------------------------------------------------
extern "C" void kernel_launch(void* const* d_in, const int* in_sizes, int n_in,
                              void* d_out, int out_size, void* d_ws, size_t ws_size,
                              hipStream_t stream) {
    const int*   x      = (const int*)d_in[0];
    const int*   mask   = (const int*)d_in[2];    // bool delivered as int32
    const float* emb    = (const float*)d_in[3];
    const float* labels = (const float*)d_in[4];
    const float* conv_w = (const float*)d_in[5];
    const float* conv_b = (const float*)d_in[6];
    const float* w1     = (const float*)d_in[7];
    const float* b1     = (const float*)d_in[8];
    const float* w2     = (const float*)d_in[9];
    const float* b2     = (const float*)d_in[10];
    float*       out    = (float*)d_out;

    float* wt_p = (float*)d_ws;             // 23040 floats
    float* Lt   = wt_p + NCH * CH_F;        // 2000 floats
    float* rnl  = Lt + C_DIM * E_DIM;       // 20 floats

    prep_kernel<<<98, 256, 0, stream>>>(conv_w, labels, wt_p, Lt, rnl);
    fused_kernel<<<B_DIM, 64, 0, stream>>>(x, mask, emb, conv_b,
                                           w1, b1, w2, b2, wt_p, Lt, rnl, out);
}

// Round 5
// 634.642 us; speedup vs baseline: 4.7120x; 1.5142x over previous
//
#include <hip/hip_runtime.h>
#include <math.h>

#define B_DIM 4096
#define S_DIM 200
#define E_DIM 100
#define C_DIM 20
#define K_DIM 51
#define PADW  25

typedef _Float16 f16x8 __attribute__((ext_vector_type(8)));
typedef float    f32x4 __attribute__((ext_vector_type(4)));

#define GT_ROWS   258            // s+k: 0..257 (row = s+k, g value at s' = row-25)
#define GT_STRIDE 144            // bytes: 32 f16 hi | 32 f16 lo | 16 pad (bank-skew)
#define NA_FRAGS  (51*2*2)       // (k, mt, split)
#define NA_SHORTS (NA_FRAGS*512) // 104448

// ---------------------------------------------------------------------------
// Prep: A-fragments of conv weights (fp16 split, x256, exact MFMA lane order),
// Lt[e*20+c] transposed labels, rnl[c] = 1/||label_c||.
// Frag element: lane l, elem j -> A[o = mt*16 + (l&15)][i = (l>>4)*8 + j]
// ---------------------------------------------------------------------------
__global__ void prep_kernel(const float* __restrict__ conv_w,
                            const float* __restrict__ labels,
                            short* __restrict__ wA,
                            float* __restrict__ Lt,
                            float* __restrict__ rnl) {
    int idx = blockIdx.x * 256 + threadIdx.x;
    if (idx < NA_SHORTS) {
        int frag  = idx >> 9;          // ((k*2+mt)*2+split)
        int r     = idx & 511;
        int lane  = r >> 3;
        int j     = r & 7;
        int split = frag & 1;
        int mt    = (frag >> 1) & 1;
        int k     = frag >> 2;
        int o = mt * 16 + (lane & 15);
        int i = (lane >> 4) * 8 + j;
        float v = 0.f;
        if (o < C_DIM && i < C_DIM) v = conv_w[(o * C_DIM + i) * K_DIM + k] * 256.f;
        _Float16 hi  = (_Float16)v;
        _Float16 val = split ? (_Float16)(v - (float)hi) : hi;
        unsigned short bits;
        __builtin_memcpy(&bits, &val, 2);
        wA[idx] = (short)bits;
    } else if (idx < NA_SHORTS + C_DIM * E_DIM) {
        int t = idx - NA_SHORTS;
        int e = t / C_DIM, c = t % C_DIM;
        Lt[t] = labels[c * E_DIM + e];
    } else if (idx < NA_SHORTS + C_DIM * E_DIM + C_DIM) {
        int c = idx - NA_SHORTS - C_DIM * E_DIM;
        float s = 0.f;
        for (int e = 0; e < E_DIM; ++e) { float v = labels[c * E_DIM + e]; s += v * v; }
        float nn = sqrtf(s);
        rnl[c] = (nn > 0.f) ? 1.f / nn : 0.f;
    }
}

// ---------------------------------------------------------------------------
// One wave per batch row.  Conv via 51 shift-GEMMs on MFMA f16 (split-3).
// ---------------------------------------------------------------------------
__launch_bounds__(64, 1)
__global__ void fused_kernel(const int* __restrict__ x,
                             const int* __restrict__ mask,     // bool -> int32
                             const float* __restrict__ emb,
                             const float* __restrict__ conv_b,
                             const float* __restrict__ w1,
                             const float* __restrict__ b1,
                             const float* __restrict__ w2,
                             const float* __restrict__ b2,
                             const short* __restrict__ wA,
                             const float* __restrict__ Lt,
                             const float* __restrict__ rnl,
                             float* __restrict__ out) {
    __shared__ __align__(16) short gT[GT_ROWS * (GT_STRIDE / 2)];   // 37152 B
    __shared__ float marr[S_DIM];
    __shared__ float bw[S_DIM];
    __shared__ int   toks[S_DIM];
    __shared__ float zsh[E_DIM];
    __shared__ float hsh[E_DIM / 2];

    const int tid = threadIdx.x;
    const int b   = blockIdx.x;
    const int n   = tid & 15;
    const int q   = tid >> 4;

    // ---- zero gT (pad rows/cols must be 0) ----
    {
        float4 z{0.f, 0.f, 0.f, 0.f};
        float4* g4 = (float4*)gT;                 // 2322 float4
        for (int j = tid; j < GT_ROWS * GT_STRIDE / 16; j += 64) g4[j] = z;
    }

    const bool own = (tid < S_DIM / 4);           // 50 owner lanes
    const int  sc  = own ? tid * 4 : S_DIM - 4;
    int tok[4], msk[4];
#pragma unroll
    for (int d = 0; d < 4; ++d) {
        tok[d] = x[b * S_DIM + sc + d];
        msk[d] = mask[b * S_DIM + sc + d];
    }
    if (own) {
#pragma unroll
        for (int d = 0; d < 4; ++d) toks[sc + d] = tok[d];
    }
    __syncthreads();

    // ---- phase 1: cosine sims (fp32 VALU) -> gT fp16 split, scaled x16 ----
    {
        float dacc[4][C_DIM];
        float n2[4] = {0.f, 0.f, 0.f, 0.f};
#pragma unroll
        for (int d = 0; d < 4; ++d)
#pragma unroll
            for (int c = 0; c < C_DIM; ++c) dacc[d][c] = 0.f;

        const float4* Lt4 = (const float4*)Lt;
        for (int j = 0; j < 25; ++j) {
            float4 r4[4];
#pragma unroll
            for (int d = 0; d < 4; ++d)
                r4[d] = *(const float4*)(emb + (size_t)tok[d] * E_DIM + j * 4);
#pragma unroll
            for (int d = 0; d < 4; ++d)
                n2[d] += r4[d].x * r4[d].x + r4[d].y * r4[d].y +
                         r4[d].z * r4[d].z + r4[d].w * r4[d].w;
#pragma unroll
            for (int u = 0; u < 4; ++u) {
                float rv[4];
#pragma unroll
                for (int d = 0; d < 4; ++d) rv[d] = ((const float*)&r4[d])[u];
#pragma unroll
                for (int qq = 0; qq < 5; ++qq) {
                    const float4 a = Lt4[(j * 4 + u) * 5 + qq];
#pragma unroll
                    for (int d = 0; d < 4; ++d) {
                        dacc[d][qq * 4 + 0] += rv[d] * a.x;
                        dacc[d][qq * 4 + 1] += rv[d] * a.y;
                        dacc[d][qq * 4 + 2] += rv[d] * a.z;
                        dacc[d][qq * 4 + 3] += rv[d] * a.w;
                    }
                }
            }
        }
        if (own) {
#pragma unroll
            for (int d = 0; d < 4; ++d) {
                const float xn    = sqrtf(n2[d]);
                const float rxn16 = (xn > 0.f) ? 16.f / xn : 0.f;
                short* grow = gT + (PADW + sc + d) * (GT_STRIDE / 2);
#pragma unroll
                for (int p = 0; p < 10; ++p) {
                    float a0 = dacc[d][2 * p + 0] * rnl[2 * p + 0] * rxn16;
                    float a1 = dacc[d][2 * p + 1] * rnl[2 * p + 1] * rxn16;
                    _Float16 h0 = (_Float16)a0, h1 = (_Float16)a1;
                    _Float16 l0 = (_Float16)(a0 - (float)h0);
                    _Float16 l1 = (_Float16)(a1 - (float)h1);
                    unsigned short u0, u1, u2, u3;
                    __builtin_memcpy(&u0, &h0, 2); __builtin_memcpy(&u1, &h1, 2);
                    __builtin_memcpy(&u2, &l0, 2); __builtin_memcpy(&u3, &l1, 2);
                    *(unsigned*)(grow + 2 * p)      = (unsigned)u0 | ((unsigned)u1 << 16);
                    *(unsigned*)(grow + 32 + 2 * p) = (unsigned)u2 | ((unsigned)u3 << 16);
                }
            }
        }
    }
    __syncthreads();

    // ---- conv: 51 shift-GEMMs, MFMA f16 split-3 ----
    f32x4 acc[13][2];
#pragma unroll
    for (int nt = 0; nt < 13; ++nt) {
        acc[nt][0] = f32x4{0.f, 0.f, 0.f, 0.f};
        acc[nt][1] = f32x4{0.f, 0.f, 0.f, 0.f};
    }

    const char* gbase = (const char*)gT + n * GT_STRIDE + q * 16;
#define LDFRAG(k, mt, split) (*(const f16x8*)(wA + (((k) * 2 + (mt)) * 2 + (split)) * 512 + tid * 8))
    f16x8 ah0 = LDFRAG(0, 0, 0), al0 = LDFRAG(0, 0, 1);
    f16x8 ah1 = LDFRAG(0, 1, 0), al1 = LDFRAG(0, 1, 1);

#pragma unroll 1
    for (int k = 0; k < K_DIM; ++k) {
        const int kn = (k < K_DIM - 1) ? k + 1 : k;
        f16x8 ph0 = LDFRAG(kn, 0, 0), pl0 = LDFRAG(kn, 0, 1);
        f16x8 ph1 = LDFRAG(kn, 1, 0), pl1 = LDFRAG(kn, 1, 1);
        const char* gk = gbase + k * GT_STRIDE;
#pragma unroll
        for (int nt = 0; nt < 13; ++nt) {
            f16x8 bh = *(const f16x8*)(gk + nt * 16 * GT_STRIDE);
            f16x8 bl = *(const f16x8*)(gk + nt * 16 * GT_STRIDE + 64);
            acc[nt][0] = __builtin_amdgcn_mfma_f32_16x16x32_f16(ah0, bh, acc[nt][0], 0, 0, 0);
            acc[nt][1] = __builtin_amdgcn_mfma_f32_16x16x32_f16(ah1, bh, acc[nt][1], 0, 0, 0);
            acc[nt][0] = __builtin_amdgcn_mfma_f32_16x16x32_f16(al0, bh, acc[nt][0], 0, 0, 0);
            acc[nt][1] = __builtin_amdgcn_mfma_f32_16x16x32_f16(al1, bh, acc[nt][1], 0, 0, 0);
            acc[nt][0] = __builtin_amdgcn_mfma_f32_16x16x32_f16(ah0, bl, acc[nt][0], 0, 0, 0);
            acc[nt][1] = __builtin_amdgcn_mfma_f32_16x16x32_f16(ah1, bl, acc[nt][1], 0, 0, 0);
        }
        ah0 = ph0; al0 = pl0; ah1 = ph1; al1 = pl1;
    }
#undef LDFRAG

    // ---- epilogue: relu+bias+channel max; D row=(lane>>4)*4+reg -> o, col=lane&15 -> s ----
    {
        const float inv = 1.f / 4096.f;
        float cb0[4], cb1[4];
#pragma unroll
        for (int r = 0; r < 4; ++r) {
            cb0[r] = conv_b[4 * q + r];
            cb1[r] = (q == 0) ? conv_b[16 + r] : 0.f;
        }
#pragma unroll
        for (int nt = 0; nt < 13; ++nt) {
            float m = 0.f;   // relu floor
#pragma unroll
            for (int r = 0; r < 4; ++r) m = fmaxf(m, acc[nt][0][r] * inv + cb0[r]);
            if (q == 0) {
#pragma unroll
                for (int r = 0; r < 4; ++r) m = fmaxf(m, acc[nt][1][r] * inv + cb1[r]);
            }
            m = fmaxf(m, __shfl_xor(m, 16));
            m = fmaxf(m, __shfl_xor(m, 32));
            const int s = nt * 16 + n;
            if (q == 0 && s < S_DIM) marr[s] = m;
        }
    }
    __syncthreads();

    // ---- softmax over s (wave-wide) ----
    {
        float mval[4];
#pragma unroll
        for (int d = 0; d < 4; ++d)
            mval[d] = (msk[d] != 0) ? marr[sc + d] : -1e13f;
        float lm = fmaxf(fmaxf(mval[0], mval[1]), fmaxf(mval[2], mval[3]));
#pragma unroll
        for (int off = 32; off > 0; off >>= 1) lm = fmaxf(lm, __shfl_xor(lm, off));
        float p[4], ps = 0.f;
#pragma unroll
        for (int d = 0; d < 4; ++d) { p[d] = expf(mval[d] - lm); ps += p[d]; }
        if (!own) ps = 0.f;
#pragma unroll
        for (int off = 32; off > 0; off >>= 1) ps += __shfl_xor(ps, off);
        const float rs = 1.f / ps;
        if (own) {
#pragma unroll
            for (int d = 0; d < 4; ++d) bw[sc + d] = p[d] * rs;
        }
    }
    __syncthreads();

    // ---- pooling: z[e] = sum_s bw[s] * emb[toks[s]][e] ----
    {
        float za = 0.f, zb = 0.f;
        for (int s = 0; s < S_DIM; ++s) {
            const float  w   = bw[s];
            const float* row = emb + (size_t)toks[s] * E_DIM;
            za += w * row[tid];
            if (tid < E_DIM - 64) zb += w * row[64 + tid];
        }
        zsh[tid] = za;
        if (tid < E_DIM - 64) zsh[64 + tid] = zb;
    }
    __syncthreads();

    // ---- MLP ----
    if (tid < E_DIM / 2) {
        float h = b1[tid];
        for (int e = 0; e < E_DIM; ++e) h += zsh[e] * w1[e * (E_DIM / 2) + tid];
        hsh[tid] = fmaxf(h, 0.f);
    }
    __syncthreads();
    if (tid < C_DIM) {
        float o = b2[tid];
#pragma unroll
        for (int j = 0; j < E_DIM / 2; ++j) o += hsh[j] * w2[j * C_DIM + tid];
        out[b * C_DIM + tid] = o;
    }
}

// ---------------------------------------------------------------------------
extern "C" void kernel_launch(void* const* d_in, const int* in_sizes, int n_in,
                              void* d_out, int out_size, void* d_ws, size_t ws_size,
                              hipStream_t stream) {
    const int*   x      = (const int*)d_in[0];
    const int*   mask   = (const int*)d_in[2];    // bool delivered as int32
    const float* emb    = (const float*)d_in[3];
    const float* labels = (const float*)d_in[4];
    const float* conv_w = (const float*)d_in[5];
    const float* conv_b = (const float*)d_in[6];
    const float* w1     = (const float*)d_in[7];
    const float* b1     = (const float*)d_in[8];
    const float* w2     = (const float*)d_in[9];
    const float* b2     = (const float*)d_in[10];
    float*       out    = (float*)d_out;

    short* wA  = (short*)d_ws;                              // 104448 shorts = 208896 B
    float* Lt  = (float*)((char*)d_ws + NA_SHORTS * 2);     // 2000 floats
    float* rnl = Lt + C_DIM * E_DIM;                        // 20 floats

    const int prep_n = NA_SHORTS + C_DIM * E_DIM + C_DIM;
    prep_kernel<<<(prep_n + 255) / 256, 256, 0, stream>>>(conv_w, labels, wA, Lt, rnl);
    fused_kernel<<<B_DIM, 64, 0, stream>>>(x, mask, emb, conv_b,
                                           w1, b1, w2, b2, wA, Lt, rnl, out);
}

// Round 6
// 417.945 us; speedup vs baseline: 7.1551x; 1.5185x over previous
//
#include <hip/hip_runtime.h>
#include <math.h>

#define B_DIM 4096
#define S_DIM 200
#define E_DIM 100
#define C_DIM 20
#define K_DIM 51
#define PADW  25

typedef _Float16 f16x8 __attribute__((ext_vector_type(8)));
typedef float    f32x4 __attribute__((ext_vector_type(4)));

#define GT_ROWS   258            // s+k: 0..257
#define GT_STRIDE 144            // bytes: 32 f16 hi | 32 f16 lo | 16 pad (bank-skew)
#define GT_BYTES  (GT_ROWS * GT_STRIDE)   // 37152
#define NA_FRAGS  (51*2*2)
#define NA_SHORTS (NA_FRAGS*512) // 104448

// ---------------------------------------------------------------------------
// Prep (unchanged from round 5 — verified): A-fragments fp16-split x256 in
// MFMA lane order; Lt[e*20+c]; rnl[c]=1/||label_c||.
// ---------------------------------------------------------------------------
__global__ void prep_kernel(const float* __restrict__ conv_w,
                            const float* __restrict__ labels,
                            short* __restrict__ wA,
                            float* __restrict__ Lt,
                            float* __restrict__ rnl) {
    int idx = blockIdx.x * 256 + threadIdx.x;
    if (idx < NA_SHORTS) {
        int frag  = idx >> 9;
        int r     = idx & 511;
        int lane  = r >> 3;
        int j     = r & 7;
        int split = frag & 1;
        int mt    = (frag >> 1) & 1;
        int k     = frag >> 2;
        int o = mt * 16 + (lane & 15);
        int i = (lane >> 4) * 8 + j;
        float v = 0.f;
        if (o < C_DIM && i < C_DIM) v = conv_w[(o * C_DIM + i) * K_DIM + k] * 256.f;
        _Float16 hi  = (_Float16)v;
        _Float16 val = split ? (_Float16)(v - (float)hi) : hi;
        unsigned short bits;
        __builtin_memcpy(&bits, &val, 2);
        wA[idx] = (short)bits;
    } else if (idx < NA_SHORTS + C_DIM * E_DIM) {
        int t = idx - NA_SHORTS;
        int e = t / C_DIM, c = t % C_DIM;
        Lt[t] = labels[c * E_DIM + e];
    } else if (idx < NA_SHORTS + C_DIM * E_DIM + C_DIM) {
        int c = idx - NA_SHORTS - C_DIM * E_DIM;
        float s = 0.f;
        for (int e = 0; e < E_DIM; ++e) { float v = labels[c * E_DIM + e]; s += v * v; }
        float nn = sqrtf(s);
        rnl[c] = (nn > 0.f) ? 1.f / nn : 0.f;
    }
}

// ---------------------------------------------------------------------------
template <int CNT>
__device__ __forceinline__ void conv_tiles(const short* __restrict__ wA,
                                           const char* gbase,   // lane's row in tile 0 of this wave
                                           f32x4 (&acc)[4][2],
                                           int lane) {
#define LDFRAG(k, mt, split) (*(const f16x8*)(wA + (((k) * 2 + (mt)) * 2 + (split)) * 512 + lane * 8))
    f16x8 ah0 = LDFRAG(0, 0, 0), al0 = LDFRAG(0, 0, 1);
    f16x8 ah1 = LDFRAG(0, 1, 0), al1 = LDFRAG(0, 1, 1);
#pragma unroll 1
    for (int k = 0; k < K_DIM; ++k) {
        const int kn = (k < K_DIM - 1) ? k + 1 : k;
        f16x8 ph0 = LDFRAG(kn, 0, 0), pl0 = LDFRAG(kn, 0, 1);
        f16x8 ph1 = LDFRAG(kn, 1, 0), pl1 = LDFRAG(kn, 1, 1);
        const char* gk = gbase + k * GT_STRIDE;
#pragma unroll
        for (int t = 0; t < CNT; ++t) {
            f16x8 bh = *(const f16x8*)(gk + t * 16 * GT_STRIDE);
            f16x8 bl = *(const f16x8*)(gk + t * 16 * GT_STRIDE + 64);
            acc[t][0] = __builtin_amdgcn_mfma_f32_16x16x32_f16(ah0, bh, acc[t][0], 0, 0, 0);
            acc[t][1] = __builtin_amdgcn_mfma_f32_16x16x32_f16(ah1, bh, acc[t][1], 0, 0, 0);
            acc[t][0] = __builtin_amdgcn_mfma_f32_16x16x32_f16(al0, bh, acc[t][0], 0, 0, 0);
            acc[t][1] = __builtin_amdgcn_mfma_f32_16x16x32_f16(al1, bh, acc[t][1], 0, 0, 0);
            acc[t][0] = __builtin_amdgcn_mfma_f32_16x16x32_f16(ah0, bl, acc[t][0], 0, 0, 0);
            acc[t][1] = __builtin_amdgcn_mfma_f32_16x16x32_f16(ah1, bl, acc[t][1], 0, 0, 0);
        }
        ah0 = ph0; al0 = pl0; ah1 = ph1; al1 = pl1;
    }
#undef LDFRAG
}

// ---------------------------------------------------------------------------
// 256 threads (4 waves) per batch row.  Shared gT image; waves split n-tiles.
// Post-conv scratch aliases the dead gT region to stay at 4 blocks/CU.
// ---------------------------------------------------------------------------
__launch_bounds__(256, 4)
__global__ void fused_kernel(const int* __restrict__ x,
                             const int* __restrict__ mask,     // bool -> int32
                             const float* __restrict__ emb,
                             const float* __restrict__ conv_b,
                             const float* __restrict__ w1,
                             const float* __restrict__ b1,
                             const float* __restrict__ w2,
                             const float* __restrict__ b2,
                             const short* __restrict__ wA,
                             const float* __restrict__ Lt,
                             const float* __restrict__ rnl,
                             float* __restrict__ out) {
    __shared__ __align__(16) char smem[GT_BYTES];   // gT, later aliased
    __shared__ int toks[S_DIM];

    short* gT   = (short*)smem;
    float* marr = (float*)(smem);            // [0,    800)   after conv
    float* red  = (float*)(smem + 1024);     // [1024, 2048)
    float* bw   = (float*)(smem + 2048);     // [2048, 2848)
    float* zp   = (float*)(smem + 3072);     // [3072, 4672)  4x100
    float* zsh  = (float*)(smem + 4672);     // [4672, 5072)
    float* hsh  = (float*)(smem + 5120);     // [5120, 5320)

    const int tid  = threadIdx.x;
    const int b    = blockIdx.x;
    const int lane = tid & 63;
    const int wv   = tid >> 6;
    const int n    = lane & 15;
    const int q    = lane >> 4;

    // ---- zero gT ----
    {
        float4 z{0.f, 0.f, 0.f, 0.f};
        float4* g4 = (float4*)gT;                        // 2322 float4
        for (int j = tid; j < GT_BYTES / 16; j += 256) g4[j] = z;
    }

    const int s   = tid;
    const bool act = (s < S_DIM);
    int tok = 0, msk = 0;
    if (act) {
        tok = x[b * S_DIM + s];
        msk = mask[b * S_DIM + s];
        toks[s] = tok;
    }
    __syncthreads();

    // ---- phase 1: cosine sims (1 s per thread, round-2 layout) -> gT ----
    if (act) {
        float dacc[C_DIM];
#pragma unroll
        for (int c = 0; c < C_DIM; ++c) dacc[c] = 0.f;
        float n2 = 0.f;
        const float4* er  = (const float4*)(emb + (size_t)tok * E_DIM);
        const float4* Lt4 = (const float4*)Lt;
        for (int j = 0; j < 25; ++j) {
            const float4 r = er[j];
            n2 += r.x * r.x + r.y * r.y + r.z * r.z + r.w * r.w;
            const float rv[4] = {r.x, r.y, r.z, r.w};
#pragma unroll
            for (int u = 0; u < 4; ++u) {
#pragma unroll
                for (int qq = 0; qq < 5; ++qq) {
                    const float4 a = Lt4[(j * 4 + u) * 5 + qq];
                    dacc[qq * 4 + 0] += rv[u] * a.x;
                    dacc[qq * 4 + 1] += rv[u] * a.y;
                    dacc[qq * 4 + 2] += rv[u] * a.z;
                    dacc[qq * 4 + 3] += rv[u] * a.w;
                }
            }
        }
        const float xn    = sqrtf(n2);
        const float rxn16 = (xn > 0.f) ? 16.f / xn : 0.f;
        short* grow = gT + (PADW + s) * (GT_STRIDE / 2);
#pragma unroll
        for (int p = 0; p < 10; ++p) {
            float a0 = dacc[2 * p + 0] * rnl[2 * p + 0] * rxn16;
            float a1 = dacc[2 * p + 1] * rnl[2 * p + 1] * rxn16;
            _Float16 h0 = (_Float16)a0, h1 = (_Float16)a1;
            _Float16 l0 = (_Float16)(a0 - (float)h0);
            _Float16 l1 = (_Float16)(a1 - (float)h1);
            unsigned short u0, u1, u2, u3;
            __builtin_memcpy(&u0, &h0, 2); __builtin_memcpy(&u1, &h1, 2);
            __builtin_memcpy(&u2, &l0, 2); __builtin_memcpy(&u3, &l1, 2);
            *(unsigned*)(grow + 2 * p)      = (unsigned)u0 | ((unsigned)u1 << 16);
            *(unsigned*)(grow + 32 + 2 * p) = (unsigned)u2 | ((unsigned)u3 << 16);
        }
    }
    __syncthreads();

    // ---- conv: waves split the 13 n-tiles (4/3/3/3) ----
    f32x4 acc[4][2];
#pragma unroll
    for (int t = 0; t < 4; ++t) {
        acc[t][0] = f32x4{0.f, 0.f, 0.f, 0.f};
        acc[t][1] = f32x4{0.f, 0.f, 0.f, 0.f};
    }
    const int nt0 = (wv == 0) ? 0 : (1 + wv * 3);      // 0,4,7,10
    const int cnt = (wv == 0) ? 4 : 3;
    const char* gbase = (const char*)gT + (nt0 * 16 + n) * GT_STRIDE + q * 16;
    if (wv == 0) conv_tiles<4>(wA, gbase, acc, lane);
    else         conv_tiles<3>(wA, gbase, acc, lane);

    __syncthreads();   // gT dead; overlay becomes live

    // ---- epilogue: relu+bias+channel max -> marr[s] ----
    {
        const float inv = 1.f / 4096.f;
        float cb0[4], cb1[4];
#pragma unroll
        for (int r = 0; r < 4; ++r) {
            cb0[r] = conv_b[4 * q + r];
            cb1[r] = (q == 0) ? conv_b[16 + r] : 0.f;
        }
        for (int t = 0; t < cnt; ++t) {
            float m = 0.f;   // relu floor
#pragma unroll
            for (int r = 0; r < 4; ++r) m = fmaxf(m, acc[t][0][r] * inv + cb0[r]);
            if (q == 0) {
#pragma unroll
                for (int r = 0; r < 4; ++r) m = fmaxf(m, acc[t][1][r] * inv + cb1[r]);
            }
            m = fmaxf(m, __shfl_xor(m, 16));
            m = fmaxf(m, __shfl_xor(m, 32));
            const int ss = (nt0 + t) * 16 + n;
            if (q == 0 && ss < S_DIM) marr[ss] = m;
        }
    }
    __syncthreads();

    // ---- softmax over s (block tree) ----
    float mval = act ? ((msk != 0) ? marr[s] : -1e13f) : -1e30f;
    red[tid] = mval;
    __syncthreads();
    for (int off = 128; off > 0; off >>= 1) {
        if (tid < off) red[tid] = fmaxf(red[tid], red[tid + off]);
        __syncthreads();
    }
    const float gmax = red[0];
    __syncthreads();
    const float p = expf(mval - gmax);
    red[tid] = act ? p : 0.f;
    __syncthreads();
    for (int off = 128; off > 0; off >>= 1) {
        if (tid < off) red[tid] += red[tid + off];
        __syncthreads();
    }
    const float gsum = red[0];
    if (act) bw[s] = p / gsum;
    __syncthreads();

    // ---- pooling: wave w sums s in [50w, 50w+50) ----
    {
        float za = 0.f, zb = 0.f;
        const int s0 = wv * 50;
        for (int ss = s0; ss < s0 + 50; ++ss) {
            const float  w   = bw[ss];
            const float* row = emb + (size_t)toks[ss] * E_DIM;
            za += w * row[lane];
            if (lane < E_DIM - 64) zb += w * row[64 + lane];
        }
        zp[wv * E_DIM + lane] = za;
        if (lane < E_DIM - 64) zp[wv * E_DIM + 64 + lane] = zb;
    }
    __syncthreads();
    if (tid < E_DIM)
        zsh[tid] = zp[tid] + zp[E_DIM + tid] + zp[2 * E_DIM + tid] + zp[3 * E_DIM + tid];
    __syncthreads();

    // ---- MLP ----
    if (tid < E_DIM / 2) {
        float h = b1[tid];
        for (int e = 0; e < E_DIM; ++e) h += zsh[e] * w1[e * (E_DIM / 2) + tid];
        hsh[tid] = fmaxf(h, 0.f);
    }
    __syncthreads();
    if (tid < C_DIM) {
        float o = b2[tid];
#pragma unroll
        for (int j = 0; j < E_DIM / 2; ++j) o += hsh[j] * w2[j * C_DIM + tid];
        out[b * C_DIM + tid] = o;
    }
}

// ---------------------------------------------------------------------------
extern "C" void kernel_launch(void* const* d_in, const int* in_sizes, int n_in,
                              void* d_out, int out_size, void* d_ws, size_t ws_size,
                              hipStream_t stream) {
    const int*   x      = (const int*)d_in[0];
    const int*   mask   = (const int*)d_in[2];    // bool delivered as int32
    const float* emb    = (const float*)d_in[3];
    const float* labels = (const float*)d_in[4];
    const float* conv_w = (const float*)d_in[5];
    const float* conv_b = (const float*)d_in[6];
    const float* w1     = (const float*)d_in[7];
    const float* b1     = (const float*)d_in[8];
    const float* w2     = (const float*)d_in[9];
    const float* b2     = (const float*)d_in[10];
    float*       out    = (float*)d_out;

    short* wA  = (short*)d_ws;                              // 208896 B
    float* Lt  = (float*)((char*)d_ws + NA_SHORTS * 2);     // 2000 floats
    float* rnl = Lt + C_DIM * E_DIM;                        // 20 floats

    const int prep_n = NA_SHORTS + C_DIM * E_DIM + C_DIM;
    prep_kernel<<<(prep_n + 255) / 256, 256, 0, stream>>>(conv_w, labels, wA, Lt, rnl);
    fused_kernel<<<B_DIM, 256, 0, stream>>>(x, mask, emb, conv_b,
                                            w1, b1, w2, b2, wA, Lt, rnl, out);
}

// Round 7
// 388.937 us; speedup vs baseline: 7.6888x; 1.0746x over previous
//
#include <hip/hip_runtime.h>
#include <math.h>

#define B_DIM 4096
#define S_DIM 200
#define E_DIM 100
#define C_DIM 20
#define K_DIM 51
#define PADW  25

typedef _Float16 f16x8 __attribute__((ext_vector_type(8)));
typedef float    f32x4 __attribute__((ext_vector_type(4)));

#define GT_ROWS   258            // s+k: 0..257
#define GT_STRIDE 144            // bytes: 64 img1 | 64 img2 | 16 pad (bank-skew)
#define GT_BYTES  (GT_ROWS * GT_STRIDE)   // 37152
#define NA_FRAGS  (K_DIM*2*2)    // (k, img, mt)
#define NA_SHORTS (NA_FRAGS*512) // 104448

// ---------------------------------------------------------------------------
// Prep: packed-K A-fragments (fp16 split x256, MFMA lane order).
//   img0 K-col r: r<20 -> a_hi[i=r] ; r>=20 -> a_lo[i=r-20]
//   img1 K-col r: r<8  -> a_lo[i=12+r]; 8<=r<28 -> a_hi[i=r-8]; else 0
// Plus Lt[e*20+c] and rnl[c].
// ---------------------------------------------------------------------------
__global__ void prep_kernel(const float* __restrict__ conv_w,
                            const float* __restrict__ labels,
                            short* __restrict__ wA,
                            float* __restrict__ Lt,
                            float* __restrict__ rnl) {
    int idx = blockIdx.x * 256 + threadIdx.x;
    if (idx < NA_SHORTS) {
        int frag = idx >> 9;           // ((k*2+img)*2+mt)
        int r    = idx & 511;
        int lane = r >> 3;
        int j    = r & 7;
        int mt   = frag & 1;
        int img  = (frag >> 1) & 1;
        int k    = frag >> 2;
        int o  = mt * 16 + (lane & 15);
        int kc = (lane >> 4) * 8 + j;  // K-col 0..31

        int i = -1, lo = 0;
        if (img == 0) {
            if (kc < 20) { i = kc;      lo = 0; }
            else         { i = kc - 20; lo = 1; }
        } else {
            if (kc < 8)       { i = 12 + kc; lo = 1; }
            else if (kc < 28) { i = kc - 8;  lo = 0; }
        }
        float v = 0.f;
        if (o < C_DIM && i >= 0) v = conv_w[(o * C_DIM + i) * K_DIM + k] * 256.f;
        _Float16 hi  = (_Float16)v;
        _Float16 val = lo ? (_Float16)(v - (float)hi) : hi;
        unsigned short bits;
        __builtin_memcpy(&bits, &val, 2);
        wA[idx] = (short)bits;
    } else if (idx < NA_SHORTS + C_DIM * E_DIM) {
        int t = idx - NA_SHORTS;
        int e = t / C_DIM, c = t % C_DIM;
        Lt[t] = labels[c * E_DIM + e];
    } else if (idx < NA_SHORTS + C_DIM * E_DIM + C_DIM) {
        int c = idx - NA_SHORTS - C_DIM * E_DIM;
        float s = 0.f;
        for (int e = 0; e < E_DIM; ++e) { float v = labels[c * E_DIM + e]; s += v * v; }
        float nn = sqrtf(s);
        rnl[c] = (nn > 0.f) ? 1.f / nn : 0.f;
    }
}

// ---------------------------------------------------------------------------
template <int CNT>
__device__ __forceinline__ void conv_tiles(const short* __restrict__ wA,
                                           const char* gbase,
                                           f32x4 (&acc)[4][2],
                                           int lane) {
#define LDFRAG(k, img, mt) (*(const f16x8*)(wA + (((k) * 2 + (img)) * 2 + (mt)) * 512 + lane * 8))
    f16x8 a00 = LDFRAG(0, 0, 0), a01 = LDFRAG(0, 0, 1);
    f16x8 a10 = LDFRAG(0, 1, 0), a11 = LDFRAG(0, 1, 1);
#pragma unroll 1
    for (int k = 0; k < K_DIM; ++k) {
        const int kn = (k < K_DIM - 1) ? k + 1 : k;
        f16x8 p00 = LDFRAG(kn, 0, 0), p01 = LDFRAG(kn, 0, 1);
        f16x8 p10 = LDFRAG(kn, 1, 0), p11 = LDFRAG(kn, 1, 1);
        const char* gk = gbase + k * GT_STRIDE;
#pragma unroll
        for (int t = 0; t < CNT; ++t) {
            f16x8 b1 = *(const f16x8*)(gk + t * 16 * GT_STRIDE);
            f16x8 b2 = *(const f16x8*)(gk + t * 16 * GT_STRIDE + 64);
            acc[t][0] = __builtin_amdgcn_mfma_f32_16x16x32_f16(a00, b1, acc[t][0], 0, 0, 0);
            acc[t][1] = __builtin_amdgcn_mfma_f32_16x16x32_f16(a01, b1, acc[t][1], 0, 0, 0);
            acc[t][0] = __builtin_amdgcn_mfma_f32_16x16x32_f16(a10, b2, acc[t][0], 0, 0, 0);
            acc[t][1] = __builtin_amdgcn_mfma_f32_16x16x32_f16(a11, b2, acc[t][1], 0, 0, 0);
        }
        a00 = p00; a01 = p01; a10 = p10; a11 = p11;
    }
#undef LDFRAG
}

// ---------------------------------------------------------------------------
// 256 threads (4 waves) per batch row.  Shared gT image; waves split n-tiles.
// ---------------------------------------------------------------------------
__launch_bounds__(256, 4)
__global__ void fused_kernel(const int* __restrict__ x,
                             const int* __restrict__ mask,     // bool -> int32
                             const float* __restrict__ emb,
                             const float* __restrict__ conv_b,
                             const float* __restrict__ w1,
                             const float* __restrict__ b1,
                             const float* __restrict__ w2,
                             const float* __restrict__ b2,
                             const short* __restrict__ wA,
                             const float* __restrict__ Lt,
                             const float* __restrict__ rnl,
                             float* __restrict__ out) {
    __shared__ __align__(16) char smem[GT_BYTES];   // gT, later aliased
    __shared__ int toks[S_DIM];

    short* gT   = (short*)smem;
    float* marr = (float*)(smem);            // [0,    800)   after conv
    float* red  = (float*)(smem + 1024);     // cross-wave scratch (8 floats)
    float* bw   = (float*)(smem + 2048);     // [2048, 2848)
    float* zp   = (float*)(smem + 3072);     // 4 x 100
    float* zsh  = (float*)(smem + 4672);
    float* hsh  = (float*)(smem + 5120);

    const int tid  = threadIdx.x;
    const int b    = blockIdx.x;
    const int lane = tid & 63;
    const int wv   = tid >> 6;
    const int n    = lane & 15;
    const int q    = lane >> 4;

    // ---- zero gT ----
    {
        float4 z{0.f, 0.f, 0.f, 0.f};
        float4* g4 = (float4*)gT;
        for (int j = tid; j < GT_BYTES / 16; j += 256) g4[j] = z;
    }

    const int s    = tid;
    const bool act = (s < S_DIM);
    int tok = 0, msk = 0;
    if (act) {
        tok = x[b * S_DIM + s];
        msk = mask[b * S_DIM + s];
        toks[s] = tok;
    }
    __syncthreads();

    // ---- phase 1: cosine sims -> gT (split f16, packed-K images) ----
    if (act) {
        float dacc[C_DIM];
#pragma unroll
        for (int c = 0; c < C_DIM; ++c) dacc[c] = 0.f;
        float n2 = 0.f;
        const float4* er  = (const float4*)(emb + (size_t)tok * E_DIM);
        const float4* Lt4 = (const float4*)Lt;
        for (int j = 0; j < 25; ++j) {
            const float4 r = er[j];
            n2 += r.x * r.x + r.y * r.y + r.z * r.z + r.w * r.w;
            const float rv[4] = {r.x, r.y, r.z, r.w};
#pragma unroll
            for (int u = 0; u < 4; ++u) {
#pragma unroll
                for (int qq = 0; qq < 5; ++qq) {
                    const float4 a = Lt4[(j * 4 + u) * 5 + qq];
                    dacc[qq * 4 + 0] += rv[u] * a.x;
                    dacc[qq * 4 + 1] += rv[u] * a.y;
                    dacc[qq * 4 + 2] += rv[u] * a.z;
                    dacc[qq * 4 + 3] += rv[u] * a.w;
                }
            }
        }
        const float xn    = sqrtf(n2);
        const float rxn16 = (xn > 0.f) ? 16.f / xn : 0.f;

        unsigned short gh[C_DIM], gl[C_DIM];
#pragma unroll
        for (int c = 0; c < C_DIM; ++c) {
            float a = dacc[c] * rnl[c] * rxn16;
            _Float16 h = (_Float16)a;
            _Float16 l = (_Float16)(a - (float)h);
            __builtin_memcpy(&gh[c], &h, 2);
            __builtin_memcpy(&gl[c], &l, 2);
        }
        unsigned* grow = (unsigned*)(gT + (PADW + s) * (GT_STRIDE / 2));
#define PK(a, b) ((unsigned)(a) | ((unsigned)(b) << 16))
        // image 1: gh[0..19], gh[0..11]
#pragma unroll
        for (int d = 0; d < 10; ++d) grow[d] = PK(gh[2 * d], gh[2 * d + 1]);
#pragma unroll
        for (int d = 0; d < 6; ++d)  grow[10 + d] = PK(gh[2 * d], gh[2 * d + 1]);
        // image 2: gh[12..19], gl[0..19], 0, 0
#pragma unroll
        for (int d = 0; d < 4; ++d)  grow[16 + d] = PK(gh[12 + 2 * d], gh[13 + 2 * d]);
#pragma unroll
        for (int d = 0; d < 10; ++d) grow[20 + d] = PK(gl[2 * d], gl[2 * d + 1]);
        grow[30] = 0u; grow[31] = 0u;
#undef PK
    }
    __syncthreads();

    // ---- conv: waves split the 13 n-tiles (4/3/3/3) ----
    f32x4 acc[4][2];
#pragma unroll
    for (int t = 0; t < 4; ++t) {
        acc[t][0] = f32x4{0.f, 0.f, 0.f, 0.f};
        acc[t][1] = f32x4{0.f, 0.f, 0.f, 0.f};
    }
    const int nt0 = (wv == 0) ? 0 : (1 + wv * 3);      // 0,4,7,10
    const int cnt = (wv == 0) ? 4 : 3;
    const char* gbase = (const char*)gT + (nt0 * 16 + n) * GT_STRIDE + q * 16;
    if (wv == 0) conv_tiles<4>(wA, gbase, acc, lane);
    else         conv_tiles<3>(wA, gbase, acc, lane);

    __syncthreads();   // gT dead; overlay becomes live

    // ---- epilogue: relu+bias+channel max -> marr[s] ----
    {
        const float inv = 1.f / 4096.f;
        float cb0[4], cb1[4];
#pragma unroll
        for (int r = 0; r < 4; ++r) {
            cb0[r] = conv_b[4 * q + r];
            cb1[r] = (q == 0) ? conv_b[16 + r] : 0.f;
        }
        for (int t = 0; t < cnt; ++t) {
            float m = 0.f;   // relu floor
#pragma unroll
            for (int r = 0; r < 4; ++r) m = fmaxf(m, acc[t][0][r] * inv + cb0[r]);
            if (q == 0) {
#pragma unroll
                for (int r = 0; r < 4; ++r) m = fmaxf(m, acc[t][1][r] * inv + cb1[r]);
            }
            m = fmaxf(m, __shfl_xor(m, 16));
            m = fmaxf(m, __shfl_xor(m, 32));
            const int ss = (nt0 + t) * 16 + n;
            if (q == 0 && ss < S_DIM) marr[ss] = m;
        }
    }
    __syncthreads();

    // ---- softmax over s: wave shuffles + 4-slot cross-wave ----
    {
        float mval = act ? ((msk != 0) ? marr[s] : -1e13f) : -1e30f;
        float lm = mval;
#pragma unroll
        for (int off = 32; off > 0; off >>= 1) lm = fmaxf(lm, __shfl_xor(lm, off));
        if (lane == 0) red[wv] = lm;
        __syncthreads();
        const float gmax = fmaxf(fmaxf(red[0], red[1]), fmaxf(red[2], red[3]));
        const float p = act ? expf(mval - gmax) : 0.f;
        float ps = p;
#pragma unroll
        for (int off = 32; off > 0; off >>= 1) ps += __shfl_xor(ps, off);
        if (lane == 0) red[4 + wv] = ps;
        __syncthreads();
        const float gsum = (red[4] + red[5]) + (red[6] + red[7]);
        if (act) bw[s] = p / gsum;
    }
    __syncthreads();

    // ---- pooling: wave w sums s in [50w, 50w+50), 2-way unrolled ----
    {
        float za0 = 0.f, zb0 = 0.f, za1 = 0.f, zb1 = 0.f;
        const int s0 = wv * 50;
        for (int ss = s0; ss < s0 + 50; ss += 2) {
            const float  w0 = bw[ss];
            const float  w1v = bw[ss + 1];
            const float* r0 = emb + (size_t)toks[ss] * E_DIM;
            const float* r1 = emb + (size_t)toks[ss + 1] * E_DIM;
            za0 += w0 * r0[lane];
            za1 += w1v * r1[lane];
            if (lane < E_DIM - 64) {
                zb0 += w0 * r0[64 + lane];
                zb1 += w1v * r1[64 + lane];
            }
        }
        zp[wv * E_DIM + lane] = za0 + za1;
        if (lane < E_DIM - 64) zp[wv * E_DIM + 64 + lane] = zb0 + zb1;
    }
    __syncthreads();
    if (tid < E_DIM)
        zsh[tid] = zp[tid] + zp[E_DIM + tid] + zp[2 * E_DIM + tid] + zp[3 * E_DIM + tid];
    __syncthreads();

    // ---- MLP ----
    if (tid < E_DIM / 2) {
        float h = b1[tid];
        for (int e = 0; e < E_DIM; ++e) h += zsh[e] * w1[e * (E_DIM / 2) + tid];
        hsh[tid] = fmaxf(h, 0.f);
    }
    __syncthreads();
    if (tid < C_DIM) {
        float o = b2[tid];
#pragma unroll
        for (int j = 0; j < E_DIM / 2; ++j) o += hsh[j] * w2[j * C_DIM + tid];
        out[b * C_DIM + tid] = o;
    }
}

// ---------------------------------------------------------------------------
extern "C" void kernel_launch(void* const* d_in, const int* in_sizes, int n_in,
                              void* d_out, int out_size, void* d_ws, size_t ws_size,
                              hipStream_t stream) {
    const int*   x      = (const int*)d_in[0];
    const int*   mask   = (const int*)d_in[2];    // bool delivered as int32
    const float* emb    = (const float*)d_in[3];
    const float* labels = (const float*)d_in[4];
    const float* conv_w = (const float*)d_in[5];
    const float* conv_b = (const float*)d_in[6];
    const float* w1     = (const float*)d_in[7];
    const float* b1     = (const float*)d_in[8];
    const float* w2     = (const float*)d_in[9];
    const float* b2     = (const float*)d_in[10];
    float*       out    = (float*)d_out;

    short* wA  = (short*)d_ws;                              // 208896 B
    float* Lt  = (float*)((char*)d_ws + NA_SHORTS * 2);     // 2000 floats
    float* rnl = Lt + C_DIM * E_DIM;                        // 20 floats

    const int prep_n = NA_SHORTS + C_DIM * E_DIM + C_DIM;
    prep_kernel<<<(prep_n + 255) / 256, 256, 0, stream>>>(conv_w, labels, wA, Lt, rnl);
    fused_kernel<<<B_DIM, 256, 0, stream>>>(x, mask, emb, conv_b,
                                            w1, b1, w2, b2, wA, Lt, rnl, out);
}

// Round 8
// 345.435 us; speedup vs baseline: 8.6571x; 1.1259x over previous
//
#include <hip/hip_runtime.h>
#include <math.h>

#define B_DIM 4096
#define S_DIM 200
#define E_DIM 100
#define C_DIM 20
#define K_DIM 51
#define PADW  25

typedef _Float16 f16x8 __attribute__((ext_vector_type(8)));
typedef float    f32x4 __attribute__((ext_vector_type(4)));

#define GT_ROWS   258            // s+k: 0..257
#define GT_STRIDE 144            // bytes: 64 img1 | 64 img2 | 16 pad (bank-skew)
#define GT_BYTES  (GT_ROWS * GT_STRIDE)   // 37152
#define NA_FRAGS  (K_DIM*2*2)    // (k, img, mt)
#define NA_SHORTS (NA_FRAGS*512) // 104448

// ---------------------------------------------------------------------------
// Prep (verified r6/r7): packed-K A-fragments (fp16 split x256, MFMA lane
// order); Lt[e*20+c]; rnl[c].
//   img0 K-col r: r<20 -> a_hi[i=r] ; r>=20 -> a_lo[i=r-20]
//   img1 K-col r: r<8  -> a_lo[i=12+r]; 8<=r<28 -> a_hi[i=r-8]; else 0
// ---------------------------------------------------------------------------
__global__ void prep_kernel(const float* __restrict__ conv_w,
                            const float* __restrict__ labels,
                            short* __restrict__ wA,
                            float* __restrict__ Lt,
                            float* __restrict__ rnl) {
    int idx = blockIdx.x * 256 + threadIdx.x;
    if (idx < NA_SHORTS) {
        int frag = idx >> 9;           // ((k*2+img)*2+mt)
        int r    = idx & 511;
        int lane = r >> 3;
        int j    = r & 7;
        int mt   = frag & 1;
        int img  = (frag >> 1) & 1;
        int k    = frag >> 2;
        int o  = mt * 16 + (lane & 15);
        int kc = (lane >> 4) * 8 + j;  // K-col 0..31

        int i = -1, lo = 0;
        if (img == 0) {
            if (kc < 20) { i = kc;      lo = 0; }
            else         { i = kc - 20; lo = 1; }
        } else {
            if (kc < 8)       { i = 12 + kc; lo = 1; }
            else if (kc < 28) { i = kc - 8;  lo = 0; }
        }
        float v = 0.f;
        if (o < C_DIM && i >= 0) v = conv_w[(o * C_DIM + i) * K_DIM + k] * 256.f;
        _Float16 hi  = (_Float16)v;
        _Float16 val = lo ? (_Float16)(v - (float)hi) : hi;
        unsigned short bits;
        __builtin_memcpy(&bits, &val, 2);
        wA[idx] = (short)bits;
    } else if (idx < NA_SHORTS + C_DIM * E_DIM) {
        int t = idx - NA_SHORTS;
        int e = t / C_DIM, c = t % C_DIM;
        Lt[t] = labels[c * E_DIM + e];
    } else if (idx < NA_SHORTS + C_DIM * E_DIM + C_DIM) {
        int c = idx - NA_SHORTS - C_DIM * E_DIM;
        float s = 0.f;
        for (int e = 0; e < E_DIM; ++e) { float v = labels[c * E_DIM + e]; s += v * v; }
        float nn = sqrtf(s);
        rnl[c] = (nn > 0.f) ? 1.f / nn : 0.f;
    }
}

// ---------------------------------------------------------------------------
// Phase-ring conv: k = p + 16j.  B-frag for (tile t, k) depends only on
// f = t*16 + k, so per phase p a ring of CNT+3 fragments (registers) serves
// all (t,j); MFMA (t,j) uses ring[t+j].  Two K-images as separate passes to
// keep VGPRs <= 128.
// ---------------------------------------------------------------------------
template <int CNT>
__device__ __forceinline__ void conv_tiles(const short* __restrict__ wA,
                                           const char* gbase,   // gT + (T0*16+n)*STRIDE + q*16
                                           f32x4 (&acc)[4][2],
                                           int lane) {
#define LDFRAG(k, img, mt) (*(const f16x8*)(wA + (((k) * 2 + (img)) * 2 + (mt)) * 512 + lane * 8))
#pragma unroll
    for (int img = 0; img < 2; ++img) {
        const char* gb = gbase + img * 64;
#pragma unroll 1
        for (int p = 0; p < 16; ++p) {
            // A-frags for this phase (k = p+16j), loaded up front
            f16x8 a0[4], a1[4];
#pragma unroll
            for (int j = 0; j < 4; ++j) {
                const int k = p + 16 * j;
                if (k < K_DIM) { a0[j] = LDFRAG(k, img, 0); a1[j] = LDFRAG(k, img, 1); }
            }
            // fragment ring
            f16x8 ring[CNT + 3];
            const int nd = (p < 3) ? (CNT + 3) : (CNT + 2);
#pragma unroll
            for (int d = 0; d < CNT + 3; ++d) {
                if (d < nd)
                    ring[d] = *(const f16x8*)(gb + (p + 16 * d) * GT_STRIDE);
            }
#pragma unroll
            for (int j = 0; j < 4; ++j) {
                if (p + 16 * j < K_DIM) {
#pragma unroll
                    for (int t = 0; t < CNT; ++t) {
                        acc[t][0] = __builtin_amdgcn_mfma_f32_16x16x32_f16(a0[j], ring[t + j], acc[t][0], 0, 0, 0);
                        acc[t][1] = __builtin_amdgcn_mfma_f32_16x16x32_f16(a1[j], ring[t + j], acc[t][1], 0, 0, 0);
                    }
                }
            }
        }
    }
#undef LDFRAG
}

// ---------------------------------------------------------------------------
// 256 threads (4 waves) per batch row.  Shared gT image; waves split n-tiles.
// ---------------------------------------------------------------------------
__launch_bounds__(256, 4)
__global__ void fused_kernel(const int* __restrict__ x,
                             const int* __restrict__ mask,     // bool -> int32
                             const float* __restrict__ emb,
                             const float* __restrict__ conv_b,
                             const float* __restrict__ w1,
                             const float* __restrict__ b1,
                             const float* __restrict__ w2,
                             const float* __restrict__ b2,
                             const short* __restrict__ wA,
                             const float* __restrict__ Lt,
                             const float* __restrict__ rnl,
                             float* __restrict__ out) {
    __shared__ __align__(16) char smem[GT_BYTES];   // gT, later aliased
    __shared__ int toks[S_DIM];

    short* gT   = (short*)smem;
    float* marr = (float*)(smem);            // [0,    800)   after conv
    float* red  = (float*)(smem + 1024);     // cross-wave scratch (8 floats)
    float* bw   = (float*)(smem + 2048);     // [2048, 2848)
    float* zp   = (float*)(smem + 3072);     // 4 x 100
    float* zsh  = (float*)(smem + 4672);
    float* hsh  = (float*)(smem + 5120);

    const int tid  = threadIdx.x;
    const int b    = blockIdx.x;
    const int lane = tid & 63;
    const int wv   = tid >> 6;
    const int n    = lane & 15;
    const int q    = lane >> 4;

    // ---- zero gT ----
    {
        float4 z{0.f, 0.f, 0.f, 0.f};
        float4* g4 = (float4*)gT;
        for (int j = tid; j < GT_BYTES / 16; j += 256) g4[j] = z;
    }

    const int s    = tid;
    const bool act = (s < S_DIM);
    int tok = 0, msk = 0;
    if (act) {
        tok = x[b * S_DIM + s];
        msk = mask[b * S_DIM + s];
        toks[s] = tok;
    }
    __syncthreads();

    // ---- phase 1: cosine sims -> gT (split f16, packed-K images) ----
    if (act) {
        float dacc[C_DIM];
#pragma unroll
        for (int c = 0; c < C_DIM; ++c) dacc[c] = 0.f;
        float n2 = 0.f;
        const float4* er  = (const float4*)(emb + (size_t)tok * E_DIM);
        const float4* Lt4 = (const float4*)Lt;
        for (int j = 0; j < 25; ++j) {
            const float4 r = er[j];
            n2 += r.x * r.x + r.y * r.y + r.z * r.z + r.w * r.w;
            const float rv[4] = {r.x, r.y, r.z, r.w};
#pragma unroll
            for (int u = 0; u < 4; ++u) {
#pragma unroll
                for (int qq = 0; qq < 5; ++qq) {
                    const float4 a = Lt4[(j * 4 + u) * 5 + qq];
                    dacc[qq * 4 + 0] += rv[u] * a.x;
                    dacc[qq * 4 + 1] += rv[u] * a.y;
                    dacc[qq * 4 + 2] += rv[u] * a.z;
                    dacc[qq * 4 + 3] += rv[u] * a.w;
                }
            }
        }
        const float xn    = sqrtf(n2);
        const float rxn16 = (xn > 0.f) ? 16.f / xn : 0.f;

        unsigned short gh[C_DIM], gl[C_DIM];
#pragma unroll
        for (int c = 0; c < C_DIM; ++c) {
            float a = dacc[c] * rnl[c] * rxn16;
            _Float16 h = (_Float16)a;
            _Float16 l = (_Float16)(a - (float)h);
            __builtin_memcpy(&gh[c], &h, 2);
            __builtin_memcpy(&gl[c], &l, 2);
        }
        unsigned* grow = (unsigned*)(gT + (PADW + s) * (GT_STRIDE / 2));
#define PK(a, b) ((unsigned)(a) | ((unsigned)(b) << 16))
        // image 1: gh[0..19], gh[0..11]
#pragma unroll
        for (int d = 0; d < 10; ++d) grow[d] = PK(gh[2 * d], gh[2 * d + 1]);
#pragma unroll
        for (int d = 0; d < 6; ++d)  grow[10 + d] = PK(gh[2 * d], gh[2 * d + 1]);
        // image 2: gh[12..19], gl[0..19], 0, 0
#pragma unroll
        for (int d = 0; d < 4; ++d)  grow[16 + d] = PK(gh[12 + 2 * d], gh[13 + 2 * d]);
#pragma unroll
        for (int d = 0; d < 10; ++d) grow[20 + d] = PK(gl[2 * d], gl[2 * d + 1]);
        grow[30] = 0u; grow[31] = 0u;
#undef PK
    }
    __syncthreads();

    // ---- conv: waves split the 13 n-tiles (4/3/3/3) ----
    f32x4 acc[4][2];
#pragma unroll
    for (int t = 0; t < 4; ++t) {
        acc[t][0] = f32x4{0.f, 0.f, 0.f, 0.f};
        acc[t][1] = f32x4{0.f, 0.f, 0.f, 0.f};
    }
    const int nt0 = (wv == 0) ? 0 : (1 + wv * 3);      // 0,4,7,10
    const int cnt = (wv == 0) ? 4 : 3;
    const char* gbase = (const char*)gT + (nt0 * 16 + n) * GT_STRIDE + q * 16;
    if (wv == 0) conv_tiles<4>(wA, gbase, acc, lane);
    else         conv_tiles<3>(wA, gbase, acc, lane);

    __syncthreads();   // gT dead; overlay becomes live

    // ---- epilogue: relu+bias+channel max -> marr[s] ----
    {
        const float inv = 1.f / 4096.f;
        float cb0[4], cb1[4];
#pragma unroll
        for (int r = 0; r < 4; ++r) {
            cb0[r] = conv_b[4 * q + r];
            cb1[r] = (q == 0) ? conv_b[16 + r] : 0.f;
        }
        for (int t = 0; t < cnt; ++t) {
            float m = 0.f;   // relu floor
#pragma unroll
            for (int r = 0; r < 4; ++r) m = fmaxf(m, acc[t][0][r] * inv + cb0[r]);
            if (q == 0) {
#pragma unroll
                for (int r = 0; r < 4; ++r) m = fmaxf(m, acc[t][1][r] * inv + cb1[r]);
            }
            m = fmaxf(m, __shfl_xor(m, 16));
            m = fmaxf(m, __shfl_xor(m, 32));
            const int ss = (nt0 + t) * 16 + n;
            if (q == 0 && ss < S_DIM) marr[ss] = m;
        }
    }
    __syncthreads();

    // ---- softmax over s: wave shuffles + 4-slot cross-wave ----
    {
        float mval = act ? ((msk != 0) ? marr[s] : -1e13f) : -1e30f;
        float lm = mval;
#pragma unroll
        for (int off = 32; off > 0; off >>= 1) lm = fmaxf(lm, __shfl_xor(lm, off));
        if (lane == 0) red[wv] = lm;
        __syncthreads();
        const float gmax = fmaxf(fmaxf(red[0], red[1]), fmaxf(red[2], red[3]));
        const float p = act ? expf(mval - gmax) : 0.f;
        float ps = p;
#pragma unroll
        for (int off = 32; off > 0; off >>= 1) ps += __shfl_xor(ps, off);
        if (lane == 0) red[4 + wv] = ps;
        __syncthreads();
        const float gsum = (red[4] + red[5]) + (red[6] + red[7]);
        if (act) bw[s] = p / gsum;
    }
    __syncthreads();

    // ---- pooling: wave w sums s in [50w, 50w+50), 2-way unrolled ----
    {
        float za0 = 0.f, zb0 = 0.f, za1 = 0.f, zb1 = 0.f;
        const int s0 = wv * 50;
        for (int ss = s0; ss < s0 + 50; ss += 2) {
            const float  w0  = bw[ss];
            const float  w1v = bw[ss + 1];
            const float* r0 = emb + (size_t)toks[ss] * E_DIM;
            const float* r1 = emb + (size_t)toks[ss + 1] * E_DIM;
            za0 += w0 * r0[lane];
            za1 += w1v * r1[lane];
            if (lane < E_DIM - 64) {
                zb0 += w0 * r0[64 + lane];
                zb1 += w1v * r1[64 + lane];
            }
        }
        zp[wv * E_DIM + lane] = za0 + za1;
        if (lane < E_DIM - 64) zp[wv * E_DIM + 64 + lane] = zb0 + zb1;
    }
    __syncthreads();
    if (tid < E_DIM)
        zsh[tid] = zp[tid] + zp[E_DIM + tid] + zp[2 * E_DIM + tid] + zp[3 * E_DIM + tid];
    __syncthreads();

    // ---- MLP ----
    if (tid < E_DIM / 2) {
        float h = b1[tid];
        for (int e = 0; e < E_DIM; ++e) h += zsh[e] * w1[e * (E_DIM / 2) + tid];
        hsh[tid] = fmaxf(h, 0.f);
    }
    __syncthreads();
    if (tid < C_DIM) {
        float o = b2[tid];
#pragma unroll
        for (int j = 0; j < E_DIM / 2; ++j) o += hsh[j] * w2[j * C_DIM + tid];
        out[b * C_DIM + tid] = o;
    }
}

// ---------------------------------------------------------------------------
extern "C" void kernel_launch(void* const* d_in, const int* in_sizes, int n_in,
                              void* d_out, int out_size, void* d_ws, size_t ws_size,
                              hipStream_t stream) {
    const int*   x      = (const int*)d_in[0];
    const int*   mask   = (const int*)d_in[2];    // bool delivered as int32
    const float* emb    = (const float*)d_in[3];
    const float* labels = (const float*)d_in[4];
    const float* conv_w = (const float*)d_in[5];
    const float* conv_b = (const float*)d_in[6];
    const float* w1     = (const float*)d_in[7];
    const float* b1     = (const float*)d_in[8];
    const float* w2     = (const float*)d_in[9];
    const float* b2     = (const float*)d_in[10];
    float*       out    = (float*)d_out;

    short* wA  = (short*)d_ws;                              // 208896 B
    float* Lt  = (float*)((char*)d_ws + NA_SHORTS * 2);     // 2000 floats
    float* rnl = Lt + C_DIM * E_DIM;                        // 20 floats

    const int prep_n = NA_SHORTS + C_DIM * E_DIM + C_DIM;
    prep_kernel<<<(prep_n + 255) / 256, 256, 0, stream>>>(conv_w, labels, wA, Lt, rnl);
    fused_kernel<<<B_DIM, 256, 0, stream>>>(x, mask, emb, conv_b,
                                            w1, b1, w2, b2, wA, Lt, rnl, out);
}